// Round 1
// baseline (177.696 us; speedup 1.0000x reference)
//
#include <hip/hip_runtime.h>
#include <hip/hip_bf16.h>

// QLSTM: quantum layer collapses to products of cosines.
// qlayer(x,th) with c_w = cos(x_w+th_w):
//   out = [c1c2c3, c0c1, c0c1c2, c0c1c2c3]
//
// Phase 1: sx[t,b,g,q] = x[t,b,:]·Wx[g][q,:], d2x[t,b] = ||x-kv[:512]||^2
// Phase 2: tiny 4-dim recurrence over T=128, 16 lanes per batch element.

#define T_STEPS 128
#define BATCH 512
#define IDIM 512

// ---------------- Phase 1 ----------------
// grid 512 blocks x 128 threads; thread-per-row; K chunked by 32 via LDS.
__global__ __launch_bounds__(128) void qlstm_p1(
    const float* __restrict__ x,
    const float* __restrict__ Wf, const float* __restrict__ Wi,
    const float* __restrict__ Wu, const float* __restrict__ Wo,
    const float* __restrict__ kv,
    float* __restrict__ ws)
{
    __shared__ __align__(16) float tile[2][128][36];  // 36-float row stride: pad, 16B aligned

    const int t  = threadIdx.x;          // local row 0..127
    const int r0 = blockIdx.x * 128;     // global row base
    const int su = t & 7;                // staging float4 col
    const int sr = t >> 3;               // staging row base

    const float* Wg[4] = {Wf, Wi, Wu, Wo};
    const float* xb = x + (size_t)r0 * IDIM;

    float4 ld[8];
#pragma unroll
    for (int i = 0; i < 8; ++i)
        ld[i] = *(const float4*)(xb + (size_t)(i * 16 + sr) * IDIM + su * 4);

    float acc[16];
#pragma unroll
    for (int s = 0; s < 16; ++s) acc[s] = 0.f;
    float d2 = 0.f;

    for (int c = 0; c < 16; ++c) {
        const int buf = c & 1;
#pragma unroll
        for (int i = 0; i < 8; ++i)
            *(float4*)&tile[buf][i * 16 + sr][su * 4] = ld[i];
        __syncthreads();

        if (c < 15) {
            const float* xc = xb + (c + 1) * 32;
#pragma unroll
            for (int i = 0; i < 8; ++i)
                ld[i] = *(const float4*)(xc + (size_t)(i * 16 + sr) * IDIM + su * 4);
        }

        const int c0 = c * 32;
#pragma unroll
        for (int u = 0; u < 8; ++u) {
            float4 xv  = *(const float4*)&tile[buf][t][u * 4];
            float4 kvv = *(const float4*)&kv[c0 + u * 4];
            float dx0 = xv.x - kvv.x, dx1 = xv.y - kvv.y;
            float dx2 = xv.z - kvv.z, dx3 = xv.w - kvv.w;
            d2 = fmaf(dx0, dx0, d2); d2 = fmaf(dx1, dx1, d2);
            d2 = fmaf(dx2, dx2, d2); d2 = fmaf(dx3, dx3, d2);
#pragma unroll
            for (int s = 0; s < 16; ++s) {
                const float* wp = Wg[s >> 2] + (size_t)(s & 3) * 516 + c0 + u * 4;
                float4 wv = *(const float4*)wp;
                acc[s] = fmaf(xv.x, wv.x, acc[s]);
                acc[s] = fmaf(xv.y, wv.y, acc[s]);
                acc[s] = fmaf(xv.z, wv.z, acc[s]);
                acc[s] = fmaf(xv.w, wv.w, acc[s]);
            }
        }
        __syncthreads();
    }

    const size_t r = (size_t)r0 + t;
    float* o = ws + r * 20;
    *(float4*)(o + 0)  = make_float4(acc[0],  acc[1],  acc[2],  acc[3]);
    *(float4*)(o + 4)  = make_float4(acc[4],  acc[5],  acc[6],  acc[7]);
    *(float4*)(o + 8)  = make_float4(acc[8],  acc[9],  acc[10], acc[11]);
    *(float4*)(o + 12) = make_float4(acc[12], acc[13], acc[14], acc[15]);
    o[16] = d2;
}

// ---------------- Phase 2 ----------------
// grid 128 blocks x 64 threads; 16 lanes per batch element b.
// lane s = g*4+q  (g: gate f/i/u/o, q: wire). hx kept in xor-relative order.
__global__ __launch_bounds__(64) void qlstm_p2(
    const float* __restrict__ ws,
    const float* __restrict__ Wf, const float* __restrict__ Wi,
    const float* __restrict__ Wu, const float* __restrict__ Wo,
    const float* __restrict__ bf, const float* __restrict__ bi,
    const float* __restrict__ bu, const float* __restrict__ bo,
    const float* __restrict__ thf, const float* __restrict__ thi,
    const float* __restrict__ thu, const float* __restrict__ tho,
    const float* __restrict__ kv,
    float* __restrict__ out)
{
    const int lane = threadIdx.x;                 // 0..63
    const int b    = blockIdx.x * 4 + (lane >> 4);
    const int s    = lane & 15;
    const int g    = s >> 2;
    const int q    = s & 3;

    const float* W  = (g == 0) ? Wf  : (g == 1) ? Wi  : (g == 2) ? Wu  : Wo;
    const float* bb = (g == 0) ? bf  : (g == 1) ? bi  : (g == 2) ? bu  : bo;
    const float* th = (g == 0) ? thf : (g == 1) ? thi : (g == 2) ? thu : tho;

    // Wh row and kv tail in xor-relative order (index k holds element q^k)
    const float wh0 = W[(size_t)q * 516 + 512 + (q ^ 0)];
    const float wh1 = W[(size_t)q * 516 + 512 + (q ^ 1)];
    const float wh2 = W[(size_t)q * 516 + 512 + (q ^ 2)];
    const float wh3 = W[(size_t)q * 516 + 512 + (q ^ 3)];
    const float bias  = bb[q];
    const float theta = th[q];
    const float kh0 = kv[512 + (q ^ 0)];
    const float kh1 = kv[512 + (q ^ 1)];
    const float kh2 = kv[512 + (q ^ 2)];
    const float kh3 = kv[512 + (q ^ 3)];

    const bool g0m = (g == 0), g1m = (g == 1), g2m = (g == 2);
    const bool q0m = (q == 0), q1m = (q == 1);
    const bool qodd = (q & 1);

    float h0 = 0.f, h1 = 0.f, h2 = 0.f, h3 = 0.f, cx = 0.f;

    float sx  = ws[(size_t)b * 20 + s];
    float d2x = ws[(size_t)b * 20 + 16];

    for (int t = 0; t < T_STEPS; ++t) {
        float sx_n = 0.f, d2_n = 0.f;
        if (t < T_STEPS - 1) {
            const size_t rn = (size_t)(t + 1) * BATCH + b;
            sx_n = ws[rn * 20 + s];
            d2_n = ws[rn * 20 + 16];
        }

        // gate scalar
        float dh0 = h0 - kh0, dh1 = h1 - kh1, dh2 = h2 - kh2, dh3 = h3 - kh3;
        float d2h = dh0 * dh0;
        d2h = fmaf(dh1, dh1, d2h);
        d2h = fmaf(dh2, dh2, d2h);
        d2h = fmaf(dh3, dh3, d2h);
        float gate = __expf(-0.001f * (d2x + d2h));

        // pre-activation for this (g,q)
        float pre = sx + bias;
        pre = fmaf(wh0, h0, pre);
        pre = fmaf(wh1, h1, pre);
        pre = fmaf(wh2, h2, pre);
        pre = fmaf(wh3, h3, pre);
        pre *= gate;

        float cang = __cosf(pre + theta);

        // cross-wire products within the gate quad (xor-relative)
        float s1 = __shfl_xor(cang, 1);
        float s2 = __shfl_xor(cang, 2);
        float s3 = __shfl_xor(cang, 3);
        float m23 = s2 * s3;
        float A  = q0m ? s1 : cang;
        float T1 = qodd ? s1 : 1.f;
        float T2 = q1m ? 1.f : m23;
        float z = A * T1 * T2;

        // activation: sigmoid for f,i,o; tanh for u (g==2)
        float tin = g2m ? (z + z) : z;
        float e  = __expf(-tin);
        float sg = 1.f / (1.f + e);
        float val = g2m ? fmaf(2.f, sg, -1.f) : sg;

        // gather all four gates' values for this wire q
        float a4  = __shfl_xor(val, 4);
        float a8  = __shfl_xor(val, 8);
        float a12 = __shfl_xor(val, 12);
        float f_ = g0m ? val : g1m ? a4  : g2m ? a8  : a12;
        float i_ = g0m ? a4  : g1m ? val : g2m ? a12 : a8;
        float u_ = g0m ? a8  : g1m ? a12 : g2m ? val : a4;
        float o_ = g0m ? a12 : g1m ? a8  : g2m ? a4  : val;

        float cn = fmaf(f_, cx, i_ * u_);
        float e2 = __expf(-2.f * cn);
        float thc = (1.f - e2) / (1.f + e2);
        float hn = o_ * thc;
        cx = cn;

        // share hx (xor-relative order)
        h0 = hn;
        h1 = __shfl_xor(hn, 1);
        h2 = __shfl_xor(hn, 2);
        h3 = __shfl_xor(hn, 3);

        if (g == 0) out[(size_t)t * (BATCH * 4) + b * 4 + q] = hn;

        sx = sx_n; d2x = d2_n;
    }

    if (g == 0) {
        const size_t base = (size_t)T_STEPS * BATCH * 4;
        out[base + b * 4 + q] = h0;
        out[base + BATCH * 4 + b * 4 + q] = cx;
    }
}

extern "C" void kernel_launch(void* const* d_in, const int* in_sizes, int n_in,
                              void* d_out, int out_size, void* d_ws, size_t ws_size,
                              hipStream_t stream) {
    const float* x   = (const float*)d_in[0];
    const float* Wf  = (const float*)d_in[1];
    const float* bf  = (const float*)d_in[2];
    const float* Wi  = (const float*)d_in[3];
    const float* bi  = (const float*)d_in[4];
    const float* Wu  = (const float*)d_in[5];
    const float* bu  = (const float*)d_in[6];
    const float* Wo  = (const float*)d_in[7];
    const float* bo  = (const float*)d_in[8];
    const float* thf = (const float*)d_in[9];
    const float* thi = (const float*)d_in[10];
    const float* thu = (const float*)d_in[11];
    const float* tho = (const float*)d_in[12];
    const float* kv  = (const float*)d_in[13];
    float* out = (float*)d_out;
    float* ws  = (float*)d_ws;   // needs 65536*20*4 = 5.24 MB

    qlstm_p1<<<512, 128, 0, stream>>>(x, Wf, Wi, Wu, Wo, kv, ws);
    qlstm_p2<<<128, 64, 0, stream>>>(ws, Wf, Wi, Wu, Wo, bf, bi, bu, bo,
                                     thf, thi, thu, tho, kv, out);
}

// Round 2
// 82.098 us; speedup vs baseline: 2.1644x; 2.1644x over previous
//
#include <hip/hip_runtime.h>
#include <hip/hip_bf16.h>

// QLSTM: quantum layer collapses to products of cosines.
// qlayer(x,th) with c_w = cos(x_w+th_w):
//   out = [c1c2c3, c0c1, c0c1c2, c0c1c2c3]
//
// Phase 1: sx[t,b,g,q] = x[t,b,:]·Wx[g][q,:], d2x[t,b] = ||x-kv[:512]||^2
//   Lane-split over K: 8 lanes per row-pair, weights LDS-resident.
// Phase 2: tiny 4-dim recurrence over T=128, 16 lanes per batch element.

#define T_STEPS 128
#define BATCH 512
#define IDIM 512

// ---------------- Phase 1 ----------------
// grid 1024 blocks x 256 threads. Block = 64 rows. Wave = 16 rows:
// group = lane>>3 handles rows {2g,2g+1}; slice = lane&7 covers 64 K-floats
// as 16 interleaved float4s (k = j*32 + slice*4).
__global__ __launch_bounds__(256) void qlstm_p1(
    const float* __restrict__ x,
    const float* __restrict__ Wf, const float* __restrict__ Wi,
    const float* __restrict__ Wu, const float* __restrict__ Wo,
    const float* __restrict__ kv,
    float* __restrict__ ws)
{
    __shared__ __align__(16) float wlds[16][IDIM];   // 32 KB
    __shared__ __align__(16) float kvlds[IDIM];      // 2 KB

    const int tid = threadIdx.x;
    const float* Wg[4] = {Wf, Wi, Wu, Wo};

    // stage weights: 16 rows x 128 float4 = 2048 float4, 8 per thread
#pragma unroll
    for (int k = 0; k < 8; ++k) {
        const int idx = tid + k * 256;        // 0..2047
        const int s   = idx >> 7;             // weight row
        const int f4  = idx & 127;            // float4 within row
        const float* src = Wg[s >> 2] + (size_t)(s & 3) * 516 + f4 * 4;
        *(float4*)&wlds[s][f4 * 4] = *(const float4*)src;
    }
    if (tid < 128)
        *(float4*)&kvlds[tid * 4] = *(const float4*)(kv + tid * 4);
    __syncthreads();

    const int lane   = tid & 63;
    const int wave   = tid >> 6;
    const int grp    = lane >> 3;
    const int slice4 = (lane & 7) * 4;
    const int rowbase = blockIdx.x * 64 + wave * 16 + grp * 2;

    const float* x0 = x + (size_t)rowbase * IDIM + slice4;
    const float* x1 = x0 + IDIM;

    float acc0[16], acc1[16];
#pragma unroll
    for (int s = 0; s < 16; ++s) { acc0[s] = 0.f; acc1[s] = 0.f; }
    float d20 = 0.f, d21 = 0.f;

    float4 xa = *(const float4*)x0;
    float4 xb = *(const float4*)x1;

#pragma unroll
    for (int j = 0; j < 16; ++j) {
        float4 xa_n, xb_n;
        if (j < 15) {
            xa_n = *(const float4*)(x0 + (j + 1) * 32);
            xb_n = *(const float4*)(x1 + (j + 1) * 32);
        }

        float4 kvv = *(const float4*)&kvlds[j * 32 + slice4];
        float da0 = xa.x - kvv.x, da1 = xa.y - kvv.y, da2 = xa.z - kvv.z, da3 = xa.w - kvv.w;
        float db0 = xb.x - kvv.x, db1 = xb.y - kvv.y, db2 = xb.z - kvv.z, db3 = xb.w - kvv.w;
        d20 = fmaf(da0, da0, d20); d20 = fmaf(da1, da1, d20);
        d20 = fmaf(da2, da2, d20); d20 = fmaf(da3, da3, d20);
        d21 = fmaf(db0, db0, d21); d21 = fmaf(db1, db1, d21);
        d21 = fmaf(db2, db2, d21); d21 = fmaf(db3, db3, d21);

#pragma unroll
        for (int s = 0; s < 16; ++s) {
            float4 w = *(const float4*)&wlds[s][j * 32 + slice4];
            acc0[s] = fmaf(xa.x, w.x, acc0[s]);
            acc0[s] = fmaf(xa.y, w.y, acc0[s]);
            acc0[s] = fmaf(xa.z, w.z, acc0[s]);
            acc0[s] = fmaf(xa.w, w.w, acc0[s]);
            acc1[s] = fmaf(xb.x, w.x, acc1[s]);
            acc1[s] = fmaf(xb.y, w.y, acc1[s]);
            acc1[s] = fmaf(xb.z, w.z, acc1[s]);
            acc1[s] = fmaf(xb.w, w.w, acc1[s]);
        }
        xa = xa_n; xb = xb_n;
    }

    // reduce across the 8 slice lanes (xor 1,2,4 within the group)
#pragma unroll
    for (int m = 1; m <= 4; m <<= 1) {
#pragma unroll
        for (int s = 0; s < 16; ++s) {
            acc0[s] += __shfl_xor(acc0[s], m);
            acc1[s] += __shfl_xor(acc1[s], m);
        }
        d20 += __shfl_xor(d20, m);
        d21 += __shfl_xor(d21, m);
    }

    if ((lane & 7) == 0) {
        float* o0 = ws + (size_t)rowbase * 20;
        *(float4*)(o0 + 0)  = make_float4(acc0[0],  acc0[1],  acc0[2],  acc0[3]);
        *(float4*)(o0 + 4)  = make_float4(acc0[4],  acc0[5],  acc0[6],  acc0[7]);
        *(float4*)(o0 + 8)  = make_float4(acc0[8],  acc0[9],  acc0[10], acc0[11]);
        *(float4*)(o0 + 12) = make_float4(acc0[12], acc0[13], acc0[14], acc0[15]);
        o0[16] = d20;
        float* o1 = o0 + 20;
        *(float4*)(o1 + 0)  = make_float4(acc1[0],  acc1[1],  acc1[2],  acc1[3]);
        *(float4*)(o1 + 4)  = make_float4(acc1[4],  acc1[5],  acc1[6],  acc1[7]);
        *(float4*)(o1 + 8)  = make_float4(acc1[8],  acc1[9],  acc1[10], acc1[11]);
        *(float4*)(o1 + 12) = make_float4(acc1[12], acc1[13], acc1[14], acc1[15]);
        o1[16] = d21;
    }
}

// ---------------- Phase 2 ----------------
// grid 128 blocks x 64 threads; 16 lanes per batch element b.
// lane s = g*4+q  (g: gate f/i/u/o, q: wire). hx kept in xor-relative order.
__global__ __launch_bounds__(64) void qlstm_p2(
    const float* __restrict__ ws,
    const float* __restrict__ Wf, const float* __restrict__ Wi,
    const float* __restrict__ Wu, const float* __restrict__ Wo,
    const float* __restrict__ bf, const float* __restrict__ bi,
    const float* __restrict__ bu, const float* __restrict__ bo,
    const float* __restrict__ thf, const float* __restrict__ thi,
    const float* __restrict__ thu, const float* __restrict__ tho,
    const float* __restrict__ kv,
    float* __restrict__ out)
{
    const int lane = threadIdx.x;                 // 0..63
    const int b    = blockIdx.x * 4 + (lane >> 4);
    const int s    = lane & 15;
    const int g    = s >> 2;
    const int q    = s & 3;

    const float* W  = (g == 0) ? Wf  : (g == 1) ? Wi  : (g == 2) ? Wu  : Wo;
    const float* bb = (g == 0) ? bf  : (g == 1) ? bi  : (g == 2) ? bu  : bo;
    const float* th = (g == 0) ? thf : (g == 1) ? thi : (g == 2) ? thu : tho;

    // Wh row and kv tail in xor-relative order (index k holds element q^k)
    const float wh0 = W[(size_t)q * 516 + 512 + (q ^ 0)];
    const float wh1 = W[(size_t)q * 516 + 512 + (q ^ 1)];
    const float wh2 = W[(size_t)q * 516 + 512 + (q ^ 2)];
    const float wh3 = W[(size_t)q * 516 + 512 + (q ^ 3)];
    const float bias  = bb[q];
    const float theta = th[q];
    const float kh0 = kv[512 + (q ^ 0)];
    const float kh1 = kv[512 + (q ^ 1)];
    const float kh2 = kv[512 + (q ^ 2)];
    const float kh3 = kv[512 + (q ^ 3)];

    const bool g0m = (g == 0), g1m = (g == 1), g2m = (g == 2);
    const bool q0m = (q == 0), q1m = (q == 1);
    const bool qodd = (q & 1);

    float h0 = 0.f, h1 = 0.f, h2 = 0.f, h3 = 0.f, cx = 0.f;

    float sx  = ws[(size_t)b * 20 + s];
    float d2x = ws[(size_t)b * 20 + 16];

    for (int t = 0; t < T_STEPS; ++t) {
        float sx_n = 0.f, d2_n = 0.f;
        if (t < T_STEPS - 1) {
            const size_t rn = (size_t)(t + 1) * BATCH + b;
            sx_n = ws[rn * 20 + s];
            d2_n = ws[rn * 20 + 16];
        }

        // gate scalar
        float dh0 = h0 - kh0, dh1 = h1 - kh1, dh2 = h2 - kh2, dh3 = h3 - kh3;
        float d2h = dh0 * dh0;
        d2h = fmaf(dh1, dh1, d2h);
        d2h = fmaf(dh2, dh2, d2h);
        d2h = fmaf(dh3, dh3, d2h);
        float gate = __expf(-0.001f * (d2x + d2h));

        // pre-activation for this (g,q)
        float pre = sx + bias;
        pre = fmaf(wh0, h0, pre);
        pre = fmaf(wh1, h1, pre);
        pre = fmaf(wh2, h2, pre);
        pre = fmaf(wh3, h3, pre);
        pre *= gate;

        float cang = __cosf(pre + theta);

        // cross-wire products within the gate quad (xor-relative)
        float s1 = __shfl_xor(cang, 1);
        float s2 = __shfl_xor(cang, 2);
        float s3 = __shfl_xor(cang, 3);
        float m23 = s2 * s3;
        float A  = q0m ? s1 : cang;
        float T1 = qodd ? s1 : 1.f;
        float T2 = q1m ? 1.f : m23;
        float z = A * T1 * T2;

        // activation: sigmoid for f,i,o; tanh for u (g==2)
        float tin = g2m ? (z + z) : z;
        float e  = __expf(-tin);
        float sg = 1.f / (1.f + e);
        float val = g2m ? fmaf(2.f, sg, -1.f) : sg;

        // gather all four gates' values for this wire q
        float a4  = __shfl_xor(val, 4);
        float a8  = __shfl_xor(val, 8);
        float a12 = __shfl_xor(val, 12);
        float f_ = g0m ? val : g1m ? a4  : g2m ? a8  : a12;
        float i_ = g0m ? a4  : g1m ? val : g2m ? a12 : a8;
        float u_ = g0m ? a8  : g1m ? a12 : g2m ? val : a4;
        float o_ = g0m ? a12 : g1m ? a8  : g2m ? a4  : val;

        float cn = fmaf(f_, cx, i_ * u_);
        float e2 = __expf(-2.f * cn);
        float thc = (1.f - e2) / (1.f + e2);
        float hn = o_ * thc;
        cx = cn;

        // share hx (xor-relative order)
        h0 = hn;
        h1 = __shfl_xor(hn, 1);
        h2 = __shfl_xor(hn, 2);
        h3 = __shfl_xor(hn, 3);

        if (g == 0) out[(size_t)t * (BATCH * 4) + b * 4 + q] = hn;

        sx = sx_n; d2x = d2_n;
    }

    if (g == 0) {
        const size_t base = (size_t)T_STEPS * BATCH * 4;
        out[base + b * 4 + q] = h0;
        out[base + BATCH * 4 + b * 4 + q] = cx;
    }
}

extern "C" void kernel_launch(void* const* d_in, const int* in_sizes, int n_in,
                              void* d_out, int out_size, void* d_ws, size_t ws_size,
                              hipStream_t stream) {
    const float* x   = (const float*)d_in[0];
    const float* Wf  = (const float*)d_in[1];
    const float* bf  = (const float*)d_in[2];
    const float* Wi  = (const float*)d_in[3];
    const float* bi  = (const float*)d_in[4];
    const float* Wu  = (const float*)d_in[5];
    const float* bu  = (const float*)d_in[6];
    const float* Wo  = (const float*)d_in[7];
    const float* bo  = (const float*)d_in[8];
    const float* thf = (const float*)d_in[9];
    const float* thi = (const float*)d_in[10];
    const float* thu = (const float*)d_in[11];
    const float* tho = (const float*)d_in[12];
    const float* kv  = (const float*)d_in[13];
    float* out = (float*)d_out;
    float* ws  = (float*)d_ws;   // needs 65536*20*4 = 5.24 MB

    qlstm_p1<<<1024, 256, 0, stream>>>(x, Wf, Wi, Wu, Wo, kv, ws);
    qlstm_p2<<<128, 64, 0, stream>>>(ws, Wf, Wi, Wu, Wo, bf, bi, bu, bo,
                                     thf, thi, thu, tho, kv, out);
}

// Round 3
// 72.217 us; speedup vs baseline: 2.4606x; 1.1368x over previous
//
#include <hip/hip_runtime.h>
#include <hip/hip_bf16.h>

// QLSTM: quantum layer collapses to products of cosines.
// qlayer(x,th) with c_w = cos(x_w+th_w): out = [c1c2c3, c0c1, c0c1c2, c0c1c2c3]
//
// Phase 1 (MFMA): sx[t,b,g,q] = x·Wx[g][q,:] via split-bf16 mfma_16x16x32;
//   d2x = ||x-kv[:512]||^2 via diag of mfma(a',a') with a' = x-kv.
// Phase 2: tiny 4-dim recurrence over T=128, 16 lanes per batch element.

#define T_STEPS 128
#define BATCH 512
#define IDIM 512

typedef __attribute__((ext_vector_type(8))) short bf16x8;
typedef __attribute__((ext_vector_type(4))) float f32x4;

static __device__ __forceinline__ short f2bf(float f) {
    union { float f; unsigned u; } v; v.f = f;
    unsigned r = v.u + 0x7fffu + ((v.u >> 16) & 1u);   // RNE
    return (short)(r >> 16);
}
static __device__ __forceinline__ float bf2f(short h) {
    union { unsigned u; float f; } v;
    v.u = ((unsigned)(unsigned short)h) << 16;
    return v.f;
}

// ---------------- Phase 1 ----------------
// grid 256 blocks x 1024 threads (16 waves). Each wave: one 16-row tile,
// K=512 in 16 steps of 32. A-frags loaded straight from global (f32),
// converted to bf16 hi/lo in registers. W bf16 hi/lo fragments in LDS.
__global__ __launch_bounds__(1024, 4) void qlstm_p1(
    const float* __restrict__ x,
    const float* __restrict__ Wf, const float* __restrict__ Wi,
    const float* __restrict__ Wu, const float* __restrict__ Wo,
    const float* __restrict__ kv,
    float* __restrict__ ws)
{
    __shared__ __align__(16) unsigned short whi[16 * 64 * 8];  // 16 KB [ks][lane][8]
    __shared__ __align__(16) unsigned short wlo[16 * 64 * 8];  // 16 KB
    __shared__ __align__(16) float kvl[IDIM];                  // 2 KB [ks][b][8]

    const int tid = threadIdx.x;

    // ---- stage W as bf16 hi/lo MFMA B-fragments ----
    {
        const int ks = tid >> 6;          // 0..15 k-step
        const int l  = tid & 63;          // fragment lane
        const int c  = l & 15;            // output col n = g*4+q
        const int b  = l >> 4;            // k-chunk
        const int g  = c >> 2, q = c & 3;
        const float* Wsel = (g == 0) ? Wf : (g == 1) ? Wi : (g == 2) ? Wu : Wo;
        const float* src = Wsel + (size_t)q * 516 + ks * 32 + b * 8;
        float4 w0 = *(const float4*)src;
        float4 w1 = *(const float4*)(src + 4);
        float wf8[8] = {w0.x, w0.y, w0.z, w0.w, w1.x, w1.y, w1.z, w1.w};
        unsigned short h8[8], l8[8];
#pragma unroll
        for (int j = 0; j < 8; ++j) {
            short h = f2bf(wf8[j]);
            h8[j] = (unsigned short)h;
            l8[j] = (unsigned short)f2bf(wf8[j] - bf2f(h));
        }
        *(uint4*)&whi[tid * 8] = *(const uint4*)h8;
        *(uint4*)&wlo[tid * 8] = *(const uint4*)l8;

        if (tid < 64) {   // kv: [ks2][b2][8] f32
            const int ks2 = tid >> 2, b2 = tid & 3;
            const float* s2 = kv + ks2 * 32 + b2 * 8;
            *(float4*)&kvl[tid * 8]     = *(const float4*)s2;
            *(float4*)&kvl[tid * 8 + 4] = *(const float4*)(s2 + 4);
        }
    }
    __syncthreads();

    const int lane  = tid & 63;
    const int wave  = tid >> 6;
    const int row16 = lane & 15;          // A row within tile
    const int kb    = lane >> 4;          // k-chunk 0..3
    const int rowbase = (blockIdx.x * 16 + wave) * 16;

    const float* xp = x + (size_t)(rowbase + row16) * IDIM + kb * 8;

    f32x4 acc1 = {0.f, 0.f, 0.f, 0.f};    // x·W^T   (cols 0..15)
    f32x4 acc3 = {0.f, 0.f, 0.f, 0.f};    // (x-kv)(x-kv)^T, diag = d2

    float4 pfa[2], pfb[2];
    pfa[0] = *(const float4*)(xp);       pfb[0] = *(const float4*)(xp + 4);
    pfa[1] = *(const float4*)(xp + 32);  pfb[1] = *(const float4*)(xp + 36);

#pragma unroll
    for (int ks = 0; ks < 16; ++ks) {
        const int sl = ks & 1;
        float xv[8] = {pfa[sl].x, pfa[sl].y, pfa[sl].z, pfa[sl].w,
                       pfb[sl].x, pfb[sl].y, pfb[sl].z, pfb[sl].w};
        if (ks + 2 < 16) {   // prefetch 2 steps ahead into the freed slot
            pfa[sl] = *(const float4*)(xp + (ks + 2) * 32);
            pfb[sl] = *(const float4*)(xp + (ks + 2) * 32 + 4);
        }

        const float* kvp = kvl + ks * 32 + kb * 8;
        float4 kva = *(const float4*)kvp;
        float4 kvb = *(const float4*)(kvp + 4);
        float kvv[8] = {kva.x, kva.y, kva.z, kva.w, kvb.x, kvb.y, kvb.z, kvb.w};

        bf16x8 ahi, alo, aph;
#pragma unroll
        for (int j = 0; j < 8; ++j) {
            short h = f2bf(xv[j]);
            ahi[j] = h;
            alo[j] = f2bf(xv[j] - bf2f(h));
            aph[j] = f2bf(xv[j] - kvv[j]);
        }

        bf16x8 wh = *(const bf16x8*)&whi[(ks * 64 + lane) * 8];
        bf16x8 wl = *(const bf16x8*)&wlo[(ks * 64 + lane) * 8];

        acc1 = __builtin_amdgcn_mfma_f32_16x16x32_bf16(ahi, wh, acc1, 0, 0, 0);
        acc1 = __builtin_amdgcn_mfma_f32_16x16x32_bf16(alo, wh, acc1, 0, 0, 0);
        acc1 = __builtin_amdgcn_mfma_f32_16x16x32_bf16(ahi, wl, acc1, 0, 0, 0);
        acc3 = __builtin_amdgcn_mfma_f32_16x16x32_bf16(aph, aph, acc3, 0, 0, 0);
    }

    // epilogue: C layout col = lane&15, row = (lane>>4)*4 + reg
    const int ccol = lane & 15;
    const int crow = (lane >> 4) * 4;
#pragma unroll
    for (int j = 0; j < 4; ++j)
        ws[(size_t)(rowbase + crow + j) * 20 + ccol] = acc1[j];
    if ((ccol >> 2) == (lane >> 4))   // diag element m = ccol lives here
        ws[(size_t)(rowbase + ccol) * 20 + 16] = acc3[ccol & 3];
}

// ---------------- Phase 2 ----------------
// grid 128 blocks x 64 threads; 16 lanes per batch element b.
// lane s = g*4+q  (g: gate f/i/u/o, q: wire). hx kept in xor-relative order.
__global__ __launch_bounds__(64) void qlstm_p2(
    const float* __restrict__ ws,
    const float* __restrict__ Wf, const float* __restrict__ Wi,
    const float* __restrict__ Wu, const float* __restrict__ Wo,
    const float* __restrict__ bf, const float* __restrict__ bi,
    const float* __restrict__ bu, const float* __restrict__ bo,
    const float* __restrict__ thf, const float* __restrict__ thi,
    const float* __restrict__ thu, const float* __restrict__ tho,
    const float* __restrict__ kv,
    float* __restrict__ out)
{
    const int lane = threadIdx.x;                 // 0..63
    const int b    = blockIdx.x * 4 + (lane >> 4);
    const int s    = lane & 15;
    const int g    = s >> 2;
    const int q    = s & 3;

    const float* W  = (g == 0) ? Wf  : (g == 1) ? Wi  : (g == 2) ? Wu  : Wo;
    const float* bb = (g == 0) ? bf  : (g == 1) ? bi  : (g == 2) ? bu  : bo;
    const float* th = (g == 0) ? thf : (g == 1) ? thi : (g == 2) ? thu : tho;

    // Wh row and kv tail in xor-relative order (index k holds element q^k)
    const float wh0 = W[(size_t)q * 516 + 512 + (q ^ 0)];
    const float wh1 = W[(size_t)q * 516 + 512 + (q ^ 1)];
    const float wh2 = W[(size_t)q * 516 + 512 + (q ^ 2)];
    const float wh3 = W[(size_t)q * 516 + 512 + (q ^ 3)];
    const float bias  = bb[q];
    const float theta = th[q];
    const float kh0 = kv[512 + (q ^ 0)];
    const float kh1 = kv[512 + (q ^ 1)];
    const float kh2 = kv[512 + (q ^ 2)];
    const float kh3 = kv[512 + (q ^ 3)];

    const bool g0m = (g == 0), g1m = (g == 1), g2m = (g == 2);
    const bool q0m = (q == 0), q1m = (q == 1);
    const bool qodd = (q & 1);

    float h0 = 0.f, h1 = 0.f, h2 = 0.f, h3 = 0.f, cx = 0.f;

    float sx  = ws[(size_t)b * 20 + s];
    float d2x = ws[(size_t)b * 20 + 16];

    for (int t = 0; t < T_STEPS; ++t) {
        float sx_n = 0.f, d2_n = 0.f;
        if (t < T_STEPS - 1) {
            const size_t rn = (size_t)(t + 1) * BATCH + b;
            sx_n = ws[rn * 20 + s];
            d2_n = ws[rn * 20 + 16];
        }

        // gate scalar
        float dh0 = h0 - kh0, dh1 = h1 - kh1, dh2 = h2 - kh2, dh3 = h3 - kh3;
        float d2h = dh0 * dh0;
        d2h = fmaf(dh1, dh1, d2h);
        d2h = fmaf(dh2, dh2, d2h);
        d2h = fmaf(dh3, dh3, d2h);
        float gate = __expf(-0.001f * (d2x + d2h));

        // pre-activation for this (g,q)
        float pre = sx + bias;
        pre = fmaf(wh0, h0, pre);
        pre = fmaf(wh1, h1, pre);
        pre = fmaf(wh2, h2, pre);
        pre = fmaf(wh3, h3, pre);
        pre *= gate;

        float cang = __cosf(pre + theta);

        // cross-wire products within the gate quad (xor-relative)
        float s1 = __shfl_xor(cang, 1);
        float s2 = __shfl_xor(cang, 2);
        float s3 = __shfl_xor(cang, 3);
        float m23 = s2 * s3;
        float A  = q0m ? s1 : cang;
        float T1 = qodd ? s1 : 1.f;
        float T2 = q1m ? 1.f : m23;
        float z = A * T1 * T2;

        // activation: sigmoid for f,i,o; tanh for u (g==2)
        float tin = g2m ? (z + z) : z;
        float e  = __expf(-tin);
        float sg = 1.f / (1.f + e);
        float val = g2m ? fmaf(2.f, sg, -1.f) : sg;

        // gather all four gates' values for this wire q
        float a4  = __shfl_xor(val, 4);
        float a8  = __shfl_xor(val, 8);
        float a12 = __shfl_xor(val, 12);
        float f_ = g0m ? val : g1m ? a4  : g2m ? a8  : a12;
        float i_ = g0m ? a4  : g1m ? val : g2m ? a12 : a8;
        float u_ = g0m ? a8  : g1m ? a12 : g2m ? val : a4;
        float o_ = g0m ? a12 : g1m ? a8  : g2m ? a4  : val;

        float cn = fmaf(f_, cx, i_ * u_);
        float e2 = __expf(-2.f * cn);
        float thc = (1.f - e2) / (1.f + e2);
        float hn = o_ * thc;
        cx = cn;

        // share hx (xor-relative order)
        h0 = hn;
        h1 = __shfl_xor(hn, 1);
        h2 = __shfl_xor(hn, 2);
        h3 = __shfl_xor(hn, 3);

        if (g == 0) out[(size_t)t * (BATCH * 4) + b * 4 + q] = hn;

        sx = sx_n; d2x = d2_n;
    }

    if (g == 0) {
        const size_t base = (size_t)T_STEPS * BATCH * 4;
        out[base + b * 4 + q] = h0;
        out[base + BATCH * 4 + b * 4 + q] = cx;
    }
}

extern "C" void kernel_launch(void* const* d_in, const int* in_sizes, int n_in,
                              void* d_out, int out_size, void* d_ws, size_t ws_size,
                              hipStream_t stream) {
    const float* x   = (const float*)d_in[0];
    const float* Wf  = (const float*)d_in[1];
    const float* bf  = (const float*)d_in[2];
    const float* Wi  = (const float*)d_in[3];
    const float* bi  = (const float*)d_in[4];
    const float* Wu  = (const float*)d_in[5];
    const float* bu  = (const float*)d_in[6];
    const float* Wo  = (const float*)d_in[7];
    const float* bo  = (const float*)d_in[8];
    const float* thf = (const float*)d_in[9];
    const float* thi = (const float*)d_in[10];
    const float* thu = (const float*)d_in[11];
    const float* tho = (const float*)d_in[12];
    const float* kv  = (const float*)d_in[13];
    float* out = (float*)d_out;
    float* ws  = (float*)d_ws;   // needs 65536*20*4 = 5.24 MB

    qlstm_p1<<<256, 1024, 0, stream>>>(x, Wf, Wi, Wu, Wo, kv, ws);
    qlstm_p2<<<128, 64, 0, stream>>>(ws, Wf, Wi, Wu, Wo, bf, bi, bu, bo,
                                     thf, thi, thu, tho, kv, out);
}

// Round 4
// 72.124 us; speedup vs baseline: 2.4638x; 1.0013x over previous
//
#include <hip/hip_runtime.h>
#include <hip/hip_bf16.h>

// QLSTM: quantum layer collapses to products of cosines.
// qlayer(x,th) with c_w = cos(x_w+th_w): out = [c1c2c3, c0c1, c0c1c2, c0c1c2c3]
//
// Phase 1 (MFMA): sx[t,b,g,q] = x·Wx[g][q,:] via split-bf16 mfma_16x16x32
//   (x_hi·W_hi + x_lo·W_hi + x_hi·W_lo); d2x = ||x-kv[:512]||^2 in exact f32.
// Phase 2: tiny 4-dim recurrence over T=128, 16 lanes per batch element.

#define T_STEPS 128
#define BATCH 512
#define IDIM 512

typedef __attribute__((ext_vector_type(8))) short bf16x8;
typedef __attribute__((ext_vector_type(4))) float f32x4;

static __device__ __forceinline__ short bfbits(__hip_bfloat16 h) {
    union { __hip_bfloat16 b; short s; } c; c.b = h; return c.s;
}

// ---------------- Phase 1 ----------------
// grid 512 blocks x 512 threads (8 waves). Each wave: one 16-row tile,
// K=512 in 16 steps of 32. A-frags loaded straight from global (f32),
// converted to bf16 hi/lo in registers. W bf16 hi/lo fragments in LDS.
__global__ __launch_bounds__(512) void qlstm_p1(
    const float* __restrict__ x,
    const float* __restrict__ Wf, const float* __restrict__ Wi,
    const float* __restrict__ Wu, const float* __restrict__ Wo,
    const float* __restrict__ kv,
    float* __restrict__ ws)
{
    __shared__ __align__(16) unsigned short whi[16 * 64 * 8];  // 16 KB [ks][lane][8]
    __shared__ __align__(16) unsigned short wlo[16 * 64 * 8];  // 16 KB
    __shared__ __align__(16) float kvl[IDIM];                  // 2 KB (linear copy)

    const int tid = threadIdx.x;

    // ---- stage W as bf16 hi/lo MFMA B-fragments ----
#pragma unroll
    for (int kk = 0; kk < 2; ++kk) {
        const int idx = tid + kk * 512;    // 0..1023 = (ks, lane)
        const int ks = idx >> 6;
        const int l  = idx & 63;
        const int c  = l & 15;             // output col n = g*4+q
        const int bq = l >> 4;             // k-chunk
        const int g  = c >> 2, q = c & 3;
        const float* Wsel = (g == 0) ? Wf : (g == 1) ? Wi : (g == 2) ? Wu : Wo;
        const float* src = Wsel + (size_t)q * 516 + ks * 32 + bq * 8;
        float4 w0 = *(const float4*)src;
        float4 w1 = *(const float4*)(src + 4);
        float wf8[8] = {w0.x, w0.y, w0.z, w0.w, w1.x, w1.y, w1.z, w1.w};
        unsigned short h8[8], l8[8];
#pragma unroll
        for (int j = 0; j < 8; ++j) {
            __hip_bfloat16 h = __float2bfloat16(wf8[j]);
            h8[j] = (unsigned short)bfbits(h);
            float r = wf8[j] - __bfloat162float(h);
            l8[j] = (unsigned short)bfbits(__float2bfloat16(r));
        }
        *(uint4*)&whi[idx * 8] = *(const uint4*)h8;
        *(uint4*)&wlo[idx * 8] = *(const uint4*)l8;
    }
    if (tid < 128)
        *(float4*)&kvl[tid * 4] = *(const float4*)(kv + tid * 4);
    __syncthreads();

    const int lane  = tid & 63;
    const int wave  = tid >> 6;
    const int row16 = lane & 15;          // A row within tile
    const int kb    = lane >> 4;          // k-chunk 0..3
    const int rowbase = (blockIdx.x * 8 + wave) * 16;

    const float* xp = x + (size_t)(rowbase + row16) * IDIM + kb * 8;

    f32x4 acc = {0.f, 0.f, 0.f, 0.f};
    float d2 = 0.f;

    float4 pA[2], pB[2];
    pA[0] = *(const float4*)(xp);       pB[0] = *(const float4*)(xp + 4);
    pA[1] = *(const float4*)(xp + 32);  pB[1] = *(const float4*)(xp + 36);

#pragma unroll
    for (int ks = 0; ks < 16; ++ks) {
        const int sl = ks & 1;
        float xf[8] = {pA[sl].x, pA[sl].y, pA[sl].z, pA[sl].w,
                       pB[sl].x, pB[sl].y, pB[sl].z, pB[sl].w};
        if (ks + 2 < 16) {   // refill the slot we just drained
            pA[sl] = *(const float4*)(xp + (ks + 2) * 32);
            pB[sl] = *(const float4*)(xp + (ks + 2) * 32 + 4);
        }

        // exact-f32 distance accumulation
        const float* kvp = &kvl[ks * 32 + kb * 8];
        float4 kva = *(const float4*)kvp;
        float4 kvb = *(const float4*)(kvp + 4);
        float kvv[8] = {kva.x, kva.y, kva.z, kva.w, kvb.x, kvb.y, kvb.z, kvb.w};
#pragma unroll
        for (int j = 0; j < 8; ++j) {
            float dx = xf[j] - kvv[j];
            d2 = fmaf(dx, dx, d2);
        }

        // split bf16 A-fragments
        bf16x8 ah, al;
#pragma unroll
        for (int j = 0; j < 8; ++j) {
            __hip_bfloat16 h = __float2bfloat16(xf[j]);
            ah[j] = bfbits(h);
            float r = xf[j] - __bfloat162float(h);
            al[j] = bfbits(__float2bfloat16(r));
        }

        bf16x8 wh = *(const bf16x8*)&whi[(ks * 64 + lane) * 8];
        bf16x8 wl = *(const bf16x8*)&wlo[(ks * 64 + lane) * 8];

        acc = __builtin_amdgcn_mfma_f32_16x16x32_bf16(ah, wh, acc, 0, 0, 0);
        acc = __builtin_amdgcn_mfma_f32_16x16x32_bf16(al, wh, acc, 0, 0, 0);
        acc = __builtin_amdgcn_mfma_f32_16x16x32_bf16(ah, wl, acc, 0, 0, 0);
    }

    // reduce d2 over the 4 kb-lanes of each row (lane bits 4,5)
    d2 += __shfl_xor(d2, 16);
    d2 += __shfl_xor(d2, 32);

    // epilogue: C layout col = lane&15, row = (lane>>4)*4 + reg
    const int ccol = lane & 15;
    const int crow = (lane >> 4) * 4;
#pragma unroll
    for (int j = 0; j < 4; ++j)
        ws[(size_t)(rowbase + crow + j) * 20 + ccol] = acc[j];
    if (lane < 16)
        ws[(size_t)(rowbase + lane) * 20 + 16] = d2;
}

// ---------------- Phase 2 ----------------
// grid 128 blocks x 64 threads; 16 lanes per batch element b.
// lane s = g*4+q  (g: gate f/i/u/o, q: wire). hx kept in xor-relative order.
__global__ __launch_bounds__(64) void qlstm_p2(
    const float* __restrict__ ws,
    const float* __restrict__ Wf, const float* __restrict__ Wi,
    const float* __restrict__ Wu, const float* __restrict__ Wo,
    const float* __restrict__ bf, const float* __restrict__ bi,
    const float* __restrict__ bu, const float* __restrict__ bo,
    const float* __restrict__ thf, const float* __restrict__ thi,
    const float* __restrict__ thu, const float* __restrict__ tho,
    const float* __restrict__ kv,
    float* __restrict__ out)
{
    const int lane = threadIdx.x;                 // 0..63
    const int b    = blockIdx.x * 4 + (lane >> 4);
    const int s    = lane & 15;
    const int g    = s >> 2;
    const int q    = s & 3;

    const float* W  = (g == 0) ? Wf  : (g == 1) ? Wi  : (g == 2) ? Wu  : Wo;
    const float* bb = (g == 0) ? bf  : (g == 1) ? bi  : (g == 2) ? bu  : bo;
    const float* th = (g == 0) ? thf : (g == 1) ? thi : (g == 2) ? thu : tho;

    // Wh row and kv tail in xor-relative order (index k holds element q^k)
    const float wh0 = W[(size_t)q * 516 + 512 + (q ^ 0)];
    const float wh1 = W[(size_t)q * 516 + 512 + (q ^ 1)];
    const float wh2 = W[(size_t)q * 516 + 512 + (q ^ 2)];
    const float wh3 = W[(size_t)q * 516 + 512 + (q ^ 3)];
    const float bias  = bb[q];
    const float theta = th[q];
    const float kh0 = kv[512 + (q ^ 0)];
    const float kh1 = kv[512 + (q ^ 1)];
    const float kh2 = kv[512 + (q ^ 2)];
    const float kh3 = kv[512 + (q ^ 3)];

    const bool g0m = (g == 0), g1m = (g == 1), g2m = (g == 2);
    const bool q0m = (q == 0), q1m = (q == 1);
    const bool qodd = (q & 1);

    float h0 = 0.f, h1 = 0.f, h2 = 0.f, h3 = 0.f, cx = 0.f;

    float sx  = ws[(size_t)b * 20 + s];
    float d2x = ws[(size_t)b * 20 + 16];

    for (int t = 0; t < T_STEPS; ++t) {
        float sx_n = 0.f, d2_n = 0.f;
        if (t < T_STEPS - 1) {
            const size_t rn = (size_t)(t + 1) * BATCH + b;
            sx_n = ws[rn * 20 + s];
            d2_n = ws[rn * 20 + 16];
        }

        // gate scalar
        float dh0 = h0 - kh0, dh1 = h1 - kh1, dh2 = h2 - kh2, dh3 = h3 - kh3;
        float d2h = dh0 * dh0;
        d2h = fmaf(dh1, dh1, d2h);
        d2h = fmaf(dh2, dh2, d2h);
        d2h = fmaf(dh3, dh3, d2h);
        float gate = __expf(-0.001f * (d2x + d2h));

        // pre-activation for this (g,q)
        float pre = sx + bias;
        pre = fmaf(wh0, h0, pre);
        pre = fmaf(wh1, h1, pre);
        pre = fmaf(wh2, h2, pre);
        pre = fmaf(wh3, h3, pre);
        pre *= gate;

        float cang = __cosf(pre + theta);

        // cross-wire products within the gate quad (xor-relative)
        float s1 = __shfl_xor(cang, 1);
        float s2 = __shfl_xor(cang, 2);
        float s3 = __shfl_xor(cang, 3);
        float m23 = s2 * s3;
        float A  = q0m ? s1 : cang;
        float T1 = qodd ? s1 : 1.f;
        float T2 = q1m ? 1.f : m23;
        float z = A * T1 * T2;

        // activation: sigmoid for f,i,o; tanh for u (g==2)
        float tin = g2m ? (z + z) : z;
        float e  = __expf(-tin);
        float sg = 1.f / (1.f + e);
        float val = g2m ? fmaf(2.f, sg, -1.f) : sg;

        // gather all four gates' values for this wire q
        float a4  = __shfl_xor(val, 4);
        float a8  = __shfl_xor(val, 8);
        float a12 = __shfl_xor(val, 12);
        float f_ = g0m ? val : g1m ? a4  : g2m ? a8  : a12;
        float i_ = g0m ? a4  : g1m ? val : g2m ? a12 : a8;
        float u_ = g0m ? a8  : g1m ? a12 : g2m ? val : a4;
        float o_ = g0m ? a12 : g1m ? a8  : g2m ? a4  : val;

        float cn = fmaf(f_, cx, i_ * u_);
        float e2 = __expf(-2.f * cn);
        float thc = (1.f - e2) / (1.f + e2);
        float hn = o_ * thc;
        cx = cn;

        // share hx (xor-relative order)
        h0 = hn;
        h1 = __shfl_xor(hn, 1);
        h2 = __shfl_xor(hn, 2);
        h3 = __shfl_xor(hn, 3);

        if (g == 0) out[(size_t)t * (BATCH * 4) + b * 4 + q] = hn;

        sx = sx_n; d2x = d2_n;
    }

    if (g == 0) {
        const size_t base = (size_t)T_STEPS * BATCH * 4;
        out[base + b * 4 + q] = h0;
        out[base + BATCH * 4 + b * 4 + q] = cx;
    }
}

extern "C" void kernel_launch(void* const* d_in, const int* in_sizes, int n_in,
                              void* d_out, int out_size, void* d_ws, size_t ws_size,
                              hipStream_t stream) {
    const float* x   = (const float*)d_in[0];
    const float* Wf  = (const float*)d_in[1];
    const float* bf  = (const float*)d_in[2];
    const float* Wi  = (const float*)d_in[3];
    const float* bi  = (const float*)d_in[4];
    const float* Wu  = (const float*)d_in[5];
    const float* bu  = (const float*)d_in[6];
    const float* Wo  = (const float*)d_in[7];
    const float* bo  = (const float*)d_in[8];
    const float* thf = (const float*)d_in[9];
    const float* thi = (const float*)d_in[10];
    const float* thu = (const float*)d_in[11];
    const float* tho = (const float*)d_in[12];
    const float* kv  = (const float*)d_in[13];
    float* out = (float*)d_out;
    float* ws  = (float*)d_ws;   // needs 65536*20*4 = 5.24 MB

    qlstm_p1<<<512, 512, 0, stream>>>(x, Wf, Wi, Wu, Wo, kv, ws);
    qlstm_p2<<<128, 64, 0, stream>>>(ws, Wf, Wi, Wu, Wo, bf, bi, bu, bo,
                                     thf, thi, thu, tho, kv, out);
}